// Round 3
// baseline (335.072 us; speedup 1.0000x reference)
//
#include <hip/hip_runtime.h>

// GraphFilter B=16,T=64,F=64,N=128,E=2,K=4 — v8: single fused streaming
// kernel, ZERO workspace. Recurrence per (b,e):
//   Q[t] = U2[t] + S^T[t]@U3[t-1]
//   P[t] = U1[t] + S^T[t]@Q[t-1]
//   Y[t] = U0[t] + S^T[t]@P[t-1]   (summed over e, + bias)
// (identical rounding chain to v6/v7: states spilled bf16 each step.)
// Block = (b, TC=8 t-chunk, 16-wide o-split). Grid 512 = 2 blocks/CU, all
// resident. Per step: x[t] and S[t,e] transposed ONCE in LDS (v0/v7 proven
// 3-phase XOR-swizzled code); P/Q/U3 states live in LDS ([o][n] B-operand
// layout, additive swizzle -> conflict-free per quarter-wave). o-siblings
// sharing the same S stream are pinned to the same XCD.
// Working set = inputs 155 MB + y 33 MB < 256 MB L3 (no workspace thrash).

namespace {
constexpr int B = 16, T = 64, F = 64, N = 128, E = 2, K = 4;
constexpr int SSW = 136;   // sS row stride (ushorts)
constexpr int SXW = 68;    // sX row stride (ushorts)
constexpr int SZW = 136;   // state row stride (ushorts)
constexpr int TC = 8;      // outputs per block
}

typedef short v8s __attribute__((ext_vector_type(8)));
typedef float v4f __attribute__((ext_vector_type(4)));

__device__ inline ushort f2bf(float f) {
  union { float f; uint u; } v; v.f = f;
  uint u = v.u;
  return (ushort)((u + 0x7fffu + ((u >> 16) & 1u)) >> 16);
}

__device__ inline uint pk2(float a, float b) {
  return (uint)f2bf(a) | ((uint)f2bf(b) << 16);
}

__global__ __launch_bounds__(256, 2) void gf_fused(
    const float* __restrict__ x, const float* __restrict__ S,
    const float* __restrict__ H, const float* __restrict__ bias,
    float* __restrict__ y) {
  __shared__ ushort sS[128 * SSW];     // 34.8 KB: S staging / S^T
  __shared__ ushort sX[128 * SXW];     // 17.4 KB: x^T [n][f]
  __shared__ ushort sSt[6][16 * SZW];  // 25.5 KB: states (e*3 + {P,Q,U3})
  // block mapping: o-split siblings (same b,chunk) land on the SAME XCD
  const int g = blockIdx.x;
  const int xcd = g & 7, loc = g >> 3;       // 64 locals per XCD
  const int os = loc & 3, unitL = loc >> 2;  // os: o-split index
  const int unit = xcd * 16 + unitL;         // [0,128) = (b, chunk)
  const int b = unit >> 3, chunk = unit & 7;
  const int t0 = chunk * TC;
  const int ob = os * 16;                    // o range [ob, ob+16)
  const int tid = threadIdx.x, w = tid >> 6, lane = tid & 63;
  const int l15 = lane & 15, q = lane >> 4;

  // zero states (first reads are many barriers away)
  for (int i = tid; i < 6 * 16 * SZW; i += 256) ((ushort*)sSt)[i] = 0;

  v4f Yac[2];
  Yac[0][0] = 0.f; Yac[0][1] = 0.f; Yac[0][2] = 0.f; Yac[0][3] = 0.f;
  Yac[1] = Yac[0];

  const int tstart = (t0 == 0) ? 0 : t0 - 3;
  for (int t = tstart; t < t0 + TC; ++t) {
    const bool skipS = (t0 != 0) && (t == t0 - 3);  // proj-only warmup step
    const bool emit = (t >= t0);

    // ---- x[b,t] fp32 [f][n] -> sX bf16 x^T [n][f] (via sS staging) ----
    {
      const float* xg = x + (size_t)(b * T + t) * (F * N);
      float4 r0[4], r1[4];
      #pragma unroll
      for (int it = 0; it < 4; ++it) {
        const int idx = tid + it * 256;
        const int m = idx >> 4, g2 = idx & 15;
        r0[it] = *(const float4*)(xg + m * N + g2 * 8);
        r1[it] = *(const float4*)(xg + m * N + g2 * 8 + 4);
      }
      #pragma unroll
      for (int it = 0; it < 4; ++it) {
        const int idx = tid + it * 256;
        const int m = idx >> 4, g2 = idx & 15;
        uint4 wv;
        wv.x = pk2(r0[it].x, r0[it].y); wv.y = pk2(r0[it].z, r0[it].w);
        wv.z = pk2(r1[it].x, r1[it].y); wv.w = pk2(r1[it].z, r1[it].w);
        *(uint4*)&sS[m * SSW + ((g2 ^ (m >> 3)) * 8)] = wv;
      }
      __syncthreads();
      const int bb = tid & 7, a2 = (tid >> 3) & 15, hh = tid >> 7;
      v8s rows[8];
      #pragma unroll
      for (int j = 0; j < 8; ++j)
        rows[j] = *(const v8s*)&sS[(8 * bb + j) * SSW + ((a2 ^ bb) * 8)];
      #pragma unroll
      for (int i = 0; i < 4; ++i) {
        const int e2 = 4 * hh + i;
        const int n = 8 * a2 + e2;
        uint4 wv;
        wv.x = (uint)(ushort)rows[0][e2] | ((uint)(ushort)rows[1][e2] << 16);
        wv.y = (uint)(ushort)rows[2][e2] | ((uint)(ushort)rows[3][e2] << 16);
        wv.z = (uint)(ushort)rows[4][e2] | ((uint)(ushort)rows[5][e2] << 16);
        wv.w = (uint)(ushort)rows[6][e2] | ((uint)(ushort)rows[7][e2] << 16);
        *(uint4*)&sX[n * SXW + 8 * bb] = wv;
      }
      __syncthreads();   // sX ready; sS free
    }

    for (int e = 0; e < E; ++e) {
      // ---- phase1: stage S[b,t,e] fp32 -> sS bf16 [m][n] swizzled ----
      if (!skipS) {
        const float* Sg = S + (size_t)((b * T + t) * E + e) * (N * N);
        #pragma unroll
        for (int half = 0; half < 2; ++half) {
          float4 r0[4], r1[4];
          #pragma unroll
          for (int it = 0; it < 4; ++it) {
            const int idx = tid + (half * 4 + it) * 256;
            const int m = idx >> 4, g2 = idx & 15;
            r0[it] = *(const float4*)(Sg + m * N + g2 * 8);
            r1[it] = *(const float4*)(Sg + m * N + g2 * 8 + 4);
          }
          #pragma unroll
          for (int it = 0; it < 4; ++it) {
            const int idx = tid + (half * 4 + it) * 256;
            const int m = idx >> 4, g2 = idx & 15;
            uint4 wv;
            wv.x = pk2(r0[it].x, r0[it].y); wv.y = pk2(r0[it].z, r0[it].w);
            wv.z = pk2(r1[it].x, r1[it].y); wv.w = pk2(r1[it].z, r1[it].w);
            *(uint4*)&sS[m * SSW + ((g2 ^ (m >> 3)) * 8)] = wv;
          }
        }
      }

      // ---- proj: U0->Y, U1->Pn, U2->Qn, U3->U3n (reads sX + global H) ----
      v4f Pn[2], Qn[2], U3n[2];
      #pragma unroll
      for (int mt = 0; mt < 2; ++mt) {
        Pn[mt][0] = 0.f; Pn[mt][1] = 0.f; Pn[mt][2] = 0.f; Pn[mt][3] = 0.f;
        Qn[mt] = Pn[mt]; U3n[mt] = Pn[mt];
      }
      {
        const float* hrow = H + ((size_t)(ob + l15) * E + e) * K * F;
        v8s xf[2][2];
        #pragma unroll
        for (int mt = 0; mt < 2; ++mt)
          #pragma unroll
          for (int fk = 0; fk < 2; ++fk)
            xf[mt][fk] = *(const v8s*)&sX[((2 * w + mt) * 16 + l15) * SXW +
                                          fk * 32 + q * 8];
        #pragma unroll
        for (int k = 0; k < 4; ++k) {
          if (k == 0 && !emit) continue;
          v8s hf[2];
          #pragma unroll
          for (int fk = 0; fk < 2; ++fk) {
            const int f0 = fk * 32 + q * 8;
            const float4 h0 = *(const float4*)(hrow + k * F + f0);
            const float4 h1 = *(const float4*)(hrow + k * F + f0 + 4);
            uint4 u;
            u.x = pk2(h0.x, h0.y); u.y = pk2(h0.z, h0.w);
            u.z = pk2(h1.x, h1.y); u.w = pk2(h1.z, h1.w);
            union { uint4 u; v8s s; } cv; cv.u = u;
            hf[fk] = cv.s;
          }
          v4f* tgt = (k == 0) ? Yac : (k == 1 ? Pn : (k == 2 ? Qn : U3n));
          #pragma unroll
          for (int fk = 0; fk < 2; ++fk)
            #pragma unroll
            for (int mt = 0; mt < 2; ++mt)
              tgt[mt] = __builtin_amdgcn_mfma_f32_16x16x32_bf16(
                  xf[mt][fk], hf[fk], tgt[mt], 0, 0, 0);
        }
      }

      if (!skipS) {
        __syncthreads();   // phase1 staging visible
        // ---- phase2/3: in-place transpose -> sS = S^T [n][m] swizzled ----
        const int a2 = tid & 15, bg = tid >> 4;
        v8s rows[8];
        #pragma unroll
        for (int j = 0; j < 8; ++j)
          rows[j] = *(const v8s*)&sS[(8 * a2 + j) * SSW + ((bg ^ a2) * 8)];
        __syncthreads();   // all reads done before in-place overwrite
        #pragma unroll
        for (int i = 0; i < 8; ++i) {
          uint4 wv;
          wv.x = (uint)(ushort)rows[0][i] | ((uint)(ushort)rows[1][i] << 16);
          wv.y = (uint)(ushort)rows[2][i] | ((uint)(ushort)rows[3][i] << 16);
          wv.z = (uint)(ushort)rows[4][i] | ((uint)(ushort)rows[5][i] << 16);
          wv.w = (uint)(ushort)rows[6][i] | ((uint)(ushort)rows[7][i] << 16);
          *(uint4*)&sS[(8 * bg + i) * SSW + ((a2 ^ bg) * 8)] = wv;
        }
        __syncthreads();   // S^T ready
        // ---- mm: Y += S^T@P; Pn += S^T@Q; Qn += S^T@U3 ----
        #pragma unroll
        for (int c = 0; c < 4; ++c) {
          const int p = ((4 * c + q) + 2 * l15) & 15;
          const int sbase = l15 * SZW + p * 8;
          const v8s bzP = *(const v8s*)&sSt[e * 3 + 0][sbase];
          const v8s bzQ = *(const v8s*)&sSt[e * 3 + 1][sbase];
          const v8s bzU = *(const v8s*)&sSt[e * 3 + 2][sbase];
          #pragma unroll
          for (int mt = 0; mt < 2; ++mt) {
            const int n = (2 * w + mt) * 16 + l15;
            const v8s af = *(const v8s*)&sS[n * SSW +
                                            ((((c << 2) | q) ^ (n >> 3)) * 8)];
            if (emit)
              Yac[mt] = __builtin_amdgcn_mfma_f32_16x16x32_bf16(
                  af, bzP, Yac[mt], 0, 0, 0);
            Pn[mt] = __builtin_amdgcn_mfma_f32_16x16x32_bf16(
                af, bzQ, Pn[mt], 0, 0, 0);
            Qn[mt] = __builtin_amdgcn_mfma_f32_16x16x32_bf16(
                af, bzU, Qn[mt], 0, 0, 0);
          }
        }
      }

      __syncthreads();   // state reads done before overwrite
      // ---- spill Pn,Qn,U3n -> sSt[e] (bf16, additive swizzle) ----
      #pragma unroll
      for (int mt = 0; mt < 2; ++mt) {
        const int cc = (2 * w + mt) * 2 + (q >> 1), h = q & 1;
        const int p = (cc + 2 * l15) & 15;
        const int base = l15 * SZW + p * 8 + h * 4;
        uint2 wv;
        wv.x = pk2(Pn[mt][0], Pn[mt][1]); wv.y = pk2(Pn[mt][2], Pn[mt][3]);
        *(uint2*)&sSt[e * 3 + 0][base] = wv;
        wv.x = pk2(Qn[mt][0], Qn[mt][1]); wv.y = pk2(Qn[mt][2], Qn[mt][3]);
        *(uint2*)&sSt[e * 3 + 1][base] = wv;
        wv.x = pk2(U3n[mt][0], U3n[mt][1]); wv.y = pk2(U3n[mt][2], U3n[mt][3]);
        *(uint2*)&sSt[e * 3 + 2][base] = wv;
      }

      // ---- emit y after e==1 ----
      if (e == 1 && emit) {
        float* yg = y + (size_t)(b * T + t) * (F * N);
        const float bv = bias[ob + l15];
        #pragma unroll
        for (int mt = 0; mt < 2; ++mt) {
          float4 v;
          v.x = Yac[mt][0] + bv; v.y = Yac[mt][1] + bv;
          v.z = Yac[mt][2] + bv; v.w = Yac[mt][3] + bv;
          *(float4*)(yg + (ob + l15) * N + (2 * w + mt) * 16 + q * 4) = v;
          Yac[mt][0] = 0.f; Yac[mt][1] = 0.f;
          Yac[mt][2] = 0.f; Yac[mt][3] = 0.f;
        }
      }
    }
  }
}

extern "C" void kernel_launch(void* const* d_in, const int* in_sizes, int n_in,
                              void* d_out, int out_size, void* d_ws, size_t ws_size,
                              hipStream_t stream) {
  const float* x    = (const float*)d_in[0];
  const float* S    = (const float*)d_in[1];
  const float* H    = (const float*)d_in[2];
  const float* bias = (const float*)d_in[3];
  float* y = (float*)d_out;
  (void)d_ws; (void)ws_size;

  gf_fused<<<512, 256, 0, stream>>>(x, S, H, bias, y);
}

// Round 4
// 294.547 us; speedup vs baseline: 1.1376x; 1.1376x over previous
//
#include <hip/hip_runtime.h>

// GraphFilter B=16,T=64,F=64,N=128,E=2,K=4 — v9: fused streaming recurrence
// (r3 structure) made latency-tolerant:
//  - tiny prep hoists x-transpose (xT bf16 [n][f]) and H (Hb bf16 [e][k][o][f])
//  - fused kernel register-prefetches the NEXT S slice (16 float4/thread)
//    during current proj/transpose/mm  -> HBM latency hidden (T14)
//  - no sX, no per-step H conversion: fewer barriers, less VALU
//  - LDS 60.3 KB -> 2 blocks/CU exactly; grid 512 = one generation, no tail
//  - s_setprio around mm MFMA cluster (blocks at diverse phases)
// Recurrence per (b,e):  Q[t] = U2[t] + S^T[t]@U3[t-1]
//                        P[t] = U1[t] + S^T[t]@Q[t-1]
//                        Y[t] = U0[t] + S^T[t]@P[t-1]  (sum over e, + bias)
// States spilled bf16 each step — rounding chain identical to r3 (passed).

namespace {
constexpr int B = 16, T = 64, F = 64, N = 128, E = 2, K = 4;
constexpr int SSW = 136;   // sS row stride (ushorts)
constexpr int SZW = 136;   // state row stride (ushorts)
constexpr int TC = 8;      // outputs per block
}

typedef short v8s __attribute__((ext_vector_type(8)));
typedef float v4f __attribute__((ext_vector_type(4)));

__device__ inline ushort f2bf(float f) {
  union { float f; uint u; } v; v.f = f;
  uint u = v.u;
  return (ushort)((u + 0x7fffu + ((u >> 16) & 1u)) >> 16);
}

__device__ inline uint pk2(float a, float b) {
  return (uint)f2bf(a) | ((uint)f2bf(b) << 16);
}

// Transpose one 64x128 fp32 tile (row stride 128) -> bf16 [128][64].
__device__ inline void tr64x128(const float* __restrict__ src,
                                ushort* __restrict__ dst, int dstride,
                                ushort* sh, int tid) {
  float4 r0[4], r1[4];
  #pragma unroll
  for (int it = 0; it < 4; ++it) {
    const int idx = tid + it * 256;
    const int m = idx >> 4, g = idx & 15;
    r0[it] = *(const float4*)(src + m * N + g * 8);
    r1[it] = *(const float4*)(src + m * N + g * 8 + 4);
  }
  #pragma unroll
  for (int it = 0; it < 4; ++it) {
    const int idx = tid + it * 256;
    const int m = idx >> 4, g = idx & 15;
    uint4 wv;
    wv.x = pk2(r0[it].x, r0[it].y); wv.y = pk2(r0[it].z, r0[it].w);
    wv.z = pk2(r1[it].x, r1[it].y); wv.w = pk2(r1[it].z, r1[it].w);
    *(uint4*)&sh[m * SSW + ((g ^ (m >> 3)) * 8)] = wv;
  }
  __syncthreads();
  const int bb = tid & 7, a = (tid >> 3) & 15, hh = tid >> 7;
  v8s rows[8];
  #pragma unroll
  for (int j = 0; j < 8; ++j)
    rows[j] = *(const v8s*)&sh[(8 * bb + j) * SSW + ((a ^ bb) * 8)];
  #pragma unroll
  for (int i = 0; i < 4; ++i) {
    const int e = 4 * hh + i;
    const int n = 8 * a + e;
    uint4 wv;
    wv.x = (uint)(ushort)rows[0][e] | ((uint)(ushort)rows[1][e] << 16);
    wv.y = (uint)(ushort)rows[2][e] | ((uint)(ushort)rows[3][e] << 16);
    wv.z = (uint)(ushort)rows[4][e] | ((uint)(ushort)rows[5][e] << 16);
    wv.w = (uint)(ushort)rows[6][e] | ((uint)(ushort)rows[7][e] << 16);
    *(uint4*)(dst + n * dstride + 8 * bb) = wv;
  }
}

// ---- prep: blocks [0,B*T): x -> xT bf16 [n][f]; [B*T,B*T+32): H -> Hb ----
__global__ __launch_bounds__(256) void gf_prep(
    const float* __restrict__ x, const float* __restrict__ H,
    ushort* __restrict__ xT, ushort* __restrict__ Hb) {
  __shared__ ushort sh[64 * SSW];
  const int bid = blockIdx.x;
  const int tid = threadIdx.x;
  if (bid < B * T) {
    tr64x128(x + (size_t)bid * F * N, xT + (size_t)bid * N * F, F, sh, tid);
  } else {
    const int hb = bid - B * T;
    const int d = (hb * 256 + tid) * 4;    // linear over [e][k][o][f]
    const int f = d & 63, o = (d >> 6) & 63, k = (d >> 12) & 3, e = (d >> 14) & 1;
    const float4 v = *(const float4*)(H + (((size_t)o * E + e) * K + k) * F + f);
    uint2 wv;
    wv.x = pk2(v.x, v.y);
    wv.y = pk2(v.z, v.w);
    *(uint2*)(Hb + d) = wv;
  }
}

// ---- fused chain ----
__global__ __launch_bounds__(256, 2) void gf_fused(
    const float* __restrict__ S, const ushort* __restrict__ xT,
    const ushort* __restrict__ Hb, const float* __restrict__ bias,
    float* __restrict__ y) {
  __shared__ ushort sS[128 * SSW];     // 34.8 KB: S staging / S^T (in-place)
  __shared__ ushort sSt[6][16 * SZW];  // 25.5 KB: states e*3 + {P,Q,U3}
  // o-split siblings (same b,chunk) pinned to the SAME XCD for S L2 locality
  const int g = blockIdx.x;
  const int xcd = g & 7, loc = g >> 3;
  const int os = loc & 3, unitL = loc >> 2;
  const int unit = xcd * 16 + unitL;         // (b, chunk)
  const int b = unit >> 3, chunk = unit & 7;
  const int t0 = chunk * TC;
  const int ob = os * 16;
  const int tid = threadIdx.x, w = tid >> 6, lane = tid & 63;
  const int l15 = lane & 15, q = lane >> 4;

  // zero states (first mm at t0==0 reads them)
  for (int i = tid; i < 6 * 16 * SZW; i += 256) ((ushort*)sSt)[i] = 0;

  v4f Yac[2];
  Yac[0][0] = 0.f; Yac[0][1] = 0.f; Yac[0][2] = 0.f; Yac[0][3] = 0.f;
  Yac[1] = Yac[0];

  const int tstart = (t0 == 0) ? 0 : t0 - 3;   // first step (proj-only if t0>0)
  const int tS0 = (t0 == 0) ? 0 : t0 - 2;      // first S-staged step

  // prologue: prefetch first staged slice (tS0, e=0) into registers
  float4 pf0[8], pf1[8];
  {
    const float* Sg = S + (size_t)((b * T + tS0) * E + 0) * (N * N);
    #pragma unroll
    for (int j = 0; j < 8; ++j) {
      const int idx = tid + j * 256;
      const int m = idx >> 4, g2 = idx & 15;
      pf0[j] = *(const float4*)(Sg + m * N + g2 * 8);
      pf1[j] = *(const float4*)(Sg + m * N + g2 * 8 + 4);
    }
  }
  __syncthreads();   // zero-fill visible

  for (int t = tstart; t < t0 + TC; ++t) {
    const bool staged = (t >= tS0);
    const bool emit = (t >= t0);
    for (int e = 0; e < E; ++e) {
      if (staged) {
        // phase1: pack prefetched fp32 -> sS bf16 [m][n], XOR-swizzled
        #pragma unroll
        for (int j = 0; j < 8; ++j) {
          const int idx = tid + j * 256;
          const int m = idx >> 4, g2 = idx & 15;
          uint4 wv;
          wv.x = pk2(pf0[j].x, pf0[j].y); wv.y = pk2(pf0[j].z, pf0[j].w);
          wv.z = pk2(pf1[j].x, pf1[j].y); wv.w = pk2(pf1[j].z, pf1[j].w);
          *(uint4*)&sS[m * SSW + ((g2 ^ (m >> 3)) * 8)] = wv;
        }
        // issue prefetch for the NEXT staged slice (drains under proj+mm)
        const int nt = (e == 0) ? t : t + 1;
        const int ne = (e == 0) ? 1 : 0;
        if (nt < t0 + TC) {
          const float* Sg = S + (size_t)((b * T + nt) * E + ne) * (N * N);
          #pragma unroll
          for (int j = 0; j < 8; ++j) {
            const int idx = tid + j * 256;
            const int m = idx >> 4, g2 = idx & 15;
            pf0[j] = *(const float4*)(Sg + m * N + g2 * 8);
            pf1[j] = *(const float4*)(Sg + m * N + g2 * 8 + 4);
          }
        }
      }

      // ---- proj: U0->Y, U1->Pn, U2->Qn, U3->U3n (global xT/Hb, no LDS) ----
      v4f Pn[2], Qn[2], U3n[2];
      #pragma unroll
      for (int mt = 0; mt < 2; ++mt) {
        Pn[mt][0] = 0.f; Pn[mt][1] = 0.f; Pn[mt][2] = 0.f; Pn[mt][3] = 0.f;
        Qn[mt] = Pn[mt]; U3n[mt] = Pn[mt];
      }
      {
        const ushort* xrow = xT + (size_t)(b * T + t) * (N * F);
        v8s xf[2][2];
        #pragma unroll
        for (int mt = 0; mt < 2; ++mt)
          #pragma unroll
          for (int fk = 0; fk < 2; ++fk)
            xf[mt][fk] = *(const v8s*)(xrow + ((2 * w + mt) * 16 + l15) * F +
                                       fk * 32 + q * 8);
        #pragma unroll
        for (int k = 0; k < 4; ++k) {
          if (k == 0 && !emit) continue;
          const ushort* hrow = Hb + ((size_t)((e * K + k) * 64) + ob + l15) * 64;
          v8s hf[2];
          hf[0] = *(const v8s*)(hrow + q * 8);
          hf[1] = *(const v8s*)(hrow + 32 + q * 8);
          v4f* tgt = (k == 0) ? Yac : (k == 1 ? Pn : (k == 2 ? Qn : U3n));
          #pragma unroll
          for (int fk = 0; fk < 2; ++fk)
            #pragma unroll
            for (int mt = 0; mt < 2; ++mt)
              tgt[mt] = __builtin_amdgcn_mfma_f32_16x16x32_bf16(
                  xf[mt][fk], hf[fk], tgt[mt], 0, 0, 0);
        }
      }

      if (staged) {
        __syncthreads();   // phase1 visible
        // phase2/3: in-place transpose -> sS = S^T [n][m] swizzled
        const int a2 = tid & 15, bg = tid >> 4;
        v8s rows[8];
        #pragma unroll
        for (int j = 0; j < 8; ++j)
          rows[j] = *(const v8s*)&sS[(8 * a2 + j) * SSW + ((bg ^ a2) * 8)];
        __syncthreads();   // all reads done before in-place overwrite
        #pragma unroll
        for (int i = 0; i < 8; ++i) {
          uint4 wv;
          wv.x = (uint)(ushort)rows[0][i] | ((uint)(ushort)rows[1][i] << 16);
          wv.y = (uint)(ushort)rows[2][i] | ((uint)(ushort)rows[3][i] << 16);
          wv.z = (uint)(ushort)rows[4][i] | ((uint)(ushort)rows[5][i] << 16);
          wv.w = (uint)(ushort)rows[6][i] | ((uint)(ushort)rows[7][i] << 16);
          *(uint4*)&sS[(8 * bg + i) * SSW + ((a2 ^ bg) * 8)] = wv;
        }
        __syncthreads();   // S^T ready
        // ---- mm: Y += S^T@P; Pn += S^T@Q; Qn += S^T@U3 ----
        __builtin_amdgcn_s_setprio(1);
        #pragma unroll
        for (int c = 0; c < 4; ++c) {
          const int p = ((4 * c + q) + 2 * l15) & 15;
          const int sbase = l15 * SZW + p * 8;
          const v8s bzP = *(const v8s*)&sSt[e * 3 + 0][sbase];
          const v8s bzQ = *(const v8s*)&sSt[e * 3 + 1][sbase];
          const v8s bzU = *(const v8s*)&sSt[e * 3 + 2][sbase];
          #pragma unroll
          for (int mt = 0; mt < 2; ++mt) {
            const int n = (2 * w + mt) * 16 + l15;
            const v8s af = *(const v8s*)&sS[n * SSW +
                                            ((((c << 2) | q) ^ (n >> 3)) * 8)];
            if (emit)
              Yac[mt] = __builtin_amdgcn_mfma_f32_16x16x32_bf16(
                  af, bzP, Yac[mt], 0, 0, 0);
            Pn[mt] = __builtin_amdgcn_mfma_f32_16x16x32_bf16(
                af, bzQ, Pn[mt], 0, 0, 0);
            Qn[mt] = __builtin_amdgcn_mfma_f32_16x16x32_bf16(
                af, bzU, Qn[mt], 0, 0, 0);
          }
        }
        __builtin_amdgcn_s_setprio(0);
      }

      __syncthreads();   // state readers done before overwrite
      // ---- spill Pn,Qn,U3n -> sSt[e] (bf16, additive swizzle) ----
      #pragma unroll
      for (int mt = 0; mt < 2; ++mt) {
        const int cc = (2 * w + mt) * 2 + (q >> 1), h = q & 1;
        const int p = (cc + 2 * l15) & 15;
        const int base = l15 * SZW + p * 8 + h * 4;
        uint2 wv;
        wv.x = pk2(Pn[mt][0], Pn[mt][1]); wv.y = pk2(Pn[mt][2], Pn[mt][3]);
        *(uint2*)&sSt[e * 3 + 0][base] = wv;
        wv.x = pk2(Qn[mt][0], Qn[mt][1]); wv.y = pk2(Qn[mt][2], Qn[mt][3]);
        *(uint2*)&sSt[e * 3 + 1][base] = wv;
        wv.x = pk2(U3n[mt][0], U3n[mt][1]); wv.y = pk2(U3n[mt][2], U3n[mt][3]);
        *(uint2*)&sSt[e * 3 + 2][base] = wv;
      }

      // ---- emit y after e==1 ----
      if (e == 1 && emit) {
        float* yg = y + (size_t)(b * T + t) * (F * N);
        const float bv = bias[ob + l15];
        #pragma unroll
        for (int mt = 0; mt < 2; ++mt) {
          float4 v;
          v.x = Yac[mt][0] + bv; v.y = Yac[mt][1] + bv;
          v.z = Yac[mt][2] + bv; v.w = Yac[mt][3] + bv;
          *(float4*)(yg + (ob + l15) * N + (2 * w + mt) * 16 + q * 4) = v;
          Yac[mt][0] = 0.f; Yac[mt][1] = 0.f;
          Yac[mt][2] = 0.f; Yac[mt][3] = 0.f;
        }
      }
    }
  }
}

extern "C" void kernel_launch(void* const* d_in, const int* in_sizes, int n_in,
                              void* d_out, int out_size, void* d_ws, size_t ws_size,
                              hipStream_t stream) {
  const float* x    = (const float*)d_in[0];
  const float* S    = (const float*)d_in[1];
  const float* H    = (const float*)d_in[2];
  const float* bias = (const float*)d_in[3];
  float* y = (float*)d_out;

  const size_t XTn = (size_t)B * T * N * F;   // 8.39M ushorts (16.8 MB)
  ushort* xT = (ushort*)d_ws;
  ushort* Hb = xT + XTn;                      // 32768 ushorts

  gf_prep <<<B * T + 32, 256, 0, stream>>>(x, H, xT, Hb);
  gf_fused<<<512,        256, 0, stream>>>(S, xT, Hb, bias, y);
}